// Round 1
// baseline (8952.565 us; speedup 1.0000x reference)
//
#include <hip/hip_runtime.h>

// ---------------------------------------------------------------------------
// PolicyNet2 forward, fp32 baseline.
// B=512 S=128 E=640 A=129 H=2048 NHEADS=10 HD=64 K_WIN=64
// ---------------------------------------------------------------------------

#define BB   512
#define SS   128
#define EE   640
#define AA   129
#define HH   2048
#define NH   10
#define HD   64

// workspace layout (bytes)
#define WS_OFF_H    0LL                                   // [65536,640] f32 (later: X = LN out)
#define WS_OFF_QKV  167772160LL                           // [65536,1920] f32
#define WS_OFF_C1   671088640LL                           // [512,2048]
#define WS_OFF_C2   675282944LL                           // [512,2048]
#define WS_OFF_C3   679477248LL                           // [512,1024]
#define WS_OFF_C4   681574400LL                           // [512,512]
#define WS_OFF_X1   682622976LL                           // [512,2048]
#define WS_OFF_X2   686817280LL                           // [512,2048]
#define WS_OFF_X3   691011584LL                           // [512,1024]
#define WS_OFF_X4   693108736LL                           // [512,512]
#define WS_ZERO_LEN 11534336LL                            // C1..C4 contiguous

// ---------------------------------------------------------------------------
// Generic fp32 GEMM:  C[m,n] (+)= sum_k A[m, k-kOffA] * B[n, k]  (+bias)(+resid)(relu)
// 128x128 tile, BK=16, 256 threads, 8x8 microtile. M,N must be multiples of 128.
// ---------------------------------------------------------------------------
struct GemmP {
    const float* A; const float* B; float* C;
    const float* bias; const float* resid;
    int lda, ldb, ldc, ldr;
    int kStart, kEnd, kChunk, kOffA;
    int act;   // 0 none, 1 relu
};

template <bool ATOMIC>
__global__ __launch_bounds__(256)
void gemm128(GemmP p) {
    __shared__ float As[16 * 128];
    __shared__ float Bs[16 * 128];
    const int tid = threadIdx.x;
    const int m0 = blockIdx.x * 128;
    const int n0 = blockIdx.y * 128;
    int kS = p.kStart + (int)blockIdx.z * p.kChunk;
    int kE = kS + p.kChunk; if (kE > p.kEnd) kE = p.kEnd;
    const int tx = tid & 15, ty = tid >> 4;

    float acc[8][8];
#pragma unroll
    for (int i = 0; i < 8; ++i)
#pragma unroll
        for (int j = 0; j < 8; ++j) acc[i][j] = 0.f;

    const bool a4 = ((p.lda & 3) == 0);
    const bool b4 = ((p.ldb & 3) == 0);

    for (int kt = kS; kt < kE; kt += 16) {
#pragma unroll
        for (int it = 0; it < 2; ++it) {
            const int slot = tid + it * 256;        // 0..511
            const int row = slot >> 2;              // 0..127
            const int kq  = (slot & 3) << 2;        // 0,4,8,12
            const int k   = kt + kq;
            // ---- A tile (stored transposed: As[k][m]) ----
            {
                const float* ap = p.A + (long long)(m0 + row) * p.lda + (k - p.kOffA);
                float4 v;
                if (a4 && (k + 4 <= kE)) {
                    v = *reinterpret_cast<const float4*>(ap);
                } else {
                    v.x = (k + 0 < kE) ? ap[0] : 0.f;
                    v.y = (k + 1 < kE) ? ap[1] : 0.f;
                    v.z = (k + 2 < kE) ? ap[2] : 0.f;
                    v.w = (k + 3 < kE) ? ap[3] : 0.f;
                }
                As[(kq + 0) * 128 + row] = v.x;
                As[(kq + 1) * 128 + row] = v.y;
                As[(kq + 2) * 128 + row] = v.z;
                As[(kq + 3) * 128 + row] = v.w;
            }
            // ---- B tile (weights, row n = output col): Bs[k][n] ----
            {
                const float* bp = p.B + (long long)(n0 + row) * p.ldb + k;
                float4 v;
                if (b4 && (k + 4 <= kE)) {
                    v = *reinterpret_cast<const float4*>(bp);
                } else {
                    v.x = (k + 0 < kE) ? bp[0] : 0.f;
                    v.y = (k + 1 < kE) ? bp[1] : 0.f;
                    v.z = (k + 2 < kE) ? bp[2] : 0.f;
                    v.w = (k + 3 < kE) ? bp[3] : 0.f;
                }
                Bs[(kq + 0) * 128 + row] = v.x;
                Bs[(kq + 1) * 128 + row] = v.y;
                Bs[(kq + 2) * 128 + row] = v.z;
                Bs[(kq + 3) * 128 + row] = v.w;
            }
        }
        __syncthreads();
#pragma unroll
        for (int kk = 0; kk < 16; ++kk) {
            float a[8], b[8];
            *reinterpret_cast<float4*>(&a[0]) = *reinterpret_cast<const float4*>(&As[kk * 128 + ty * 8]);
            *reinterpret_cast<float4*>(&a[4]) = *reinterpret_cast<const float4*>(&As[kk * 128 + ty * 8 + 4]);
            *reinterpret_cast<float4*>(&b[0]) = *reinterpret_cast<const float4*>(&Bs[kk * 128 + tx * 8]);
            *reinterpret_cast<float4*>(&b[4]) = *reinterpret_cast<const float4*>(&Bs[kk * 128 + tx * 8 + 4]);
#pragma unroll
            for (int i = 0; i < 8; ++i)
#pragma unroll
                for (int j = 0; j < 8; ++j) acc[i][j] += a[i] * b[j];
        }
        __syncthreads();
    }

#pragma unroll
    for (int i = 0; i < 8; ++i) {
        const int row = m0 + ty * 8 + i;
        const long long cb = (long long)row * p.ldc + n0 + tx * 8;
        if (ATOMIC) {
#pragma unroll
            for (int j = 0; j < 8; ++j) unsafeAtomicAdd(&p.C[cb + j], acc[i][j]);
        } else {
            const long long rb = (long long)row * p.ldr + n0 + tx * 8;
#pragma unroll
            for (int j = 0; j < 8; ++j) {
                float v = acc[i][j];
                if (p.bias)  v += p.bias[n0 + tx * 8 + j];
                if (p.resid) v += p.resid[rb + j];
                if (p.act)   v = fmaxf(v, 0.f);
                p.C[cb + j] = v;
            }
        }
    }
}

// ---------------------------------------------------------------------------
// Attention: one workgroup per (b, head). S=128, d=64. In-place: ctx -> q slice.
// LDS: q[128][65] + k[128][65] + scores[128][129]  = 132,608 B  (gfx950: 160 KiB)
// ---------------------------------------------------------------------------
__global__ __launch_bounds__(256)
void attn_kernel(float* qkv) {
    __shared__ float qs[128 * 65];
    __shared__ float ks[128 * 65];
    __shared__ float sc[128 * 129];
    const int tid = threadIdx.x;
    const int b = blockIdx.x / NH, h = blockIdx.x % NH;
    const long long base = (long long)b * SS * (3 * EE) + h * HD;

    for (int idx = tid; idx < 128 * 64; idx += 256) {
        const int s = idx >> 6, d = idx & 63;
        qs[s * 65 + d] = qkv[base + (long long)s * 1920 + d] * 0.125f;   // HD^-0.5
        ks[s * 65 + d] = qkv[base + 640 + (long long)s * 1920 + d];
    }
    __syncthreads();

    {   // scores: 8x8 per thread
        const int tx = tid & 15, ty = tid >> 4;
        const int i0 = ty * 8, j0 = tx * 8;
        float acc[8][8];
#pragma unroll
        for (int i = 0; i < 8; ++i)
#pragma unroll
            for (int j = 0; j < 8; ++j) acc[i][j] = 0.f;
#pragma unroll 4
        for (int d = 0; d < 64; ++d) {
            float qa[8], kb[8];
#pragma unroll
            for (int i = 0; i < 8; ++i) qa[i] = qs[(i0 + i) * 65 + d];
#pragma unroll
            for (int j = 0; j < 8; ++j) kb[j] = ks[(j0 + j) * 65 + d];
#pragma unroll
            for (int i = 0; i < 8; ++i)
#pragma unroll
                for (int j = 0; j < 8; ++j) acc[i][j] += qa[i] * kb[j];
        }
#pragma unroll
        for (int i = 0; i < 8; ++i)
#pragma unroll
            for (int j = 0; j < 8; ++j) sc[(i0 + i) * 129 + (j0 + j)] = acc[i][j];
    }
    __syncthreads();

    if (tid < 128) {   // row softmax
        const int r = tid;
        float m = -3.402823466e38f;
        for (int j = 0; j < 128; ++j) m = fmaxf(m, sc[r * 129 + j]);
        float sum = 0.f;
        for (int j = 0; j < 128; ++j) {
            const float e = expf(sc[r * 129 + j] - m);
            sc[r * 129 + j] = e; sum += e;
        }
        const float inv = 1.f / sum;
        for (int j = 0; j < 128; ++j) sc[r * 129 + j] *= inv;
    }
    __syncthreads();

    for (int idx = tid; idx < 128 * 64; idx += 256) {   // v into qs
        const int s = idx >> 6, d = idx & 63;
        qs[s * 65 + d] = qkv[base + 1280 + (long long)s * 1920 + d];
    }
    __syncthreads();

    {   // ctx = attn @ v : 4 rows x 8 cols per thread; write over q slice
        const int cx = tid & 7, cy = tid >> 3;
        const int i0 = cy * 4, d0 = cx * 8;
        float acc[4][8];
#pragma unroll
        for (int i = 0; i < 4; ++i)
#pragma unroll
            for (int j = 0; j < 8; ++j) acc[i][j] = 0.f;
#pragma unroll 4
        for (int j = 0; j < 128; ++j) {
            float aa[4], vv[8];
#pragma unroll
            for (int i = 0; i < 4; ++i) aa[i] = sc[(i0 + i) * 129 + j];
#pragma unroll
            for (int t = 0; t < 8; ++t) vv[t] = qs[j * 65 + d0 + t];
#pragma unroll
            for (int i = 0; i < 4; ++i)
#pragma unroll
                for (int t = 0; t < 8; ++t) acc[i][t] += aa[i] * vv[t];
        }
#pragma unroll
        for (int i = 0; i < 4; ++i)
#pragma unroll
            for (int t = 0; t < 8; ++t)
                qkv[base + (long long)(i0 + i) * 1920 + d0 + t] = acc[i][t];
    }
}

// ---------------------------------------------------------------------------
// LayerNorm over 640 cols (attention block): out = LN(in)*g + b. Wave per row.
// in stride 1920 (qkv k-slice), out stride 640.
// ---------------------------------------------------------------------------
__global__ __launch_bounds__(256)
void ln640_kernel(const float* in, float* out, const float* g, const float* bb) {
    const int wave = threadIdx.x >> 6, lane = threadIdx.x & 63;
    const long long row = (long long)blockIdx.x * 4 + wave;
    const float* x = in + row * 1920;
    float v[10]; float s = 0.f;
#pragma unroll
    for (int i = 0; i < 10; ++i) { v[i] = x[lane + i * 64]; s += v[i]; }
#pragma unroll
    for (int o = 32; o; o >>= 1) s += __shfl_xor(s, o);
    const float mean = s * (1.f / 640.f);
    float vs = 0.f;
#pragma unroll
    for (int i = 0; i < 10; ++i) { const float d = v[i] - mean; vs += d * d; }
#pragma unroll
    for (int o = 32; o; o >>= 1) vs += __shfl_xor(vs, o);
    const float rstd = 1.f / sqrtf(vs * (1.f / 640.f) + 1e-5f);
#pragma unroll
    for (int i = 0; i < 10; ++i) {
        const int c = lane + i * 64;
        out[row * 640 + c] = (v[i] - mean) * rstd * g[c] + bb[c];
    }
}

// ---------------------------------------------------------------------------
// X2 = LN( relu(C2 + b2) + X1 ) * g + b   over 2048 cols. Wave per row.
// ---------------------------------------------------------------------------
__global__ __launch_bounds__(256)
void ln2048_kernel(const float* c2, const float* b2, const float* x1,
                   const float* g, const float* bb, float* out) {
    const int wave = threadIdx.x >> 6, lane = threadIdx.x & 63;
    const long long row = (long long)blockIdx.x * 4 + wave;
    float v[32]; float s = 0.f;
#pragma unroll
    for (int i = 0; i < 32; ++i) {
        const int c = lane + i * 64;
        float t = fmaxf(c2[row * 2048 + c] + b2[c], 0.f) + x1[row * 2048 + c];
        v[i] = t; s += t;
    }
#pragma unroll
    for (int o = 32; o; o >>= 1) s += __shfl_xor(s, o);
    const float mean = s * (1.f / 2048.f);
    float vs = 0.f;
#pragma unroll
    for (int i = 0; i < 32; ++i) { const float d = v[i] - mean; vs += d * d; }
#pragma unroll
    for (int o = 32; o; o >>= 1) vs += __shfl_xor(vs, o);
    const float rstd = 1.f / sqrtf(vs * (1.f / 2048.f) + 1e-5f);
#pragma unroll
    for (int i = 0; i < 32; ++i) {
        const int c = lane + i * 64;
        out[row * 2048 + c] = (v[i] - mean) * rstd * g[c] + bb[c];
    }
}

// ---------------------------------------------------------------------------
// out[i] = relu(c[i] + bias[i & mask])
// ---------------------------------------------------------------------------
__global__ __launch_bounds__(256)
void bias_relu_kernel(const float* c, const float* bias, float* out, int mask) {
    const int idx = blockIdx.x * 256 + threadIdx.x;
    out[idx] = fmaxf(c[idx] + bias[idx & mask], 0.f);
}

// ---------------------------------------------------------------------------
// Head: fc5 -> concat(last_action) -> fc6 -> exact top-64 rank mask -> softmax.
// One workgroup (256 thr) per batch row.
// ---------------------------------------------------------------------------
__global__ __launch_bounds__(256)
void head_kernel(const float* x4, const float* la,
                 const float* w5, const float* b5,
                 const float* w6, const float* b6, float* out) {
    __shared__ float xs[512];
    __shared__ float ys[258];
    __shared__ float scs[132];
    __shared__ int   win[132];
    __shared__ float red[2];
    const int b = blockIdx.x, tid = threadIdx.x;
    const int wave = tid >> 6, lane = tid & 63;

    xs[tid]       = x4[b * 512 + tid];
    xs[tid + 256] = x4[b * 512 + tid + 256];
    if (tid < 129) ys[129 + tid] = la[b * 129 + tid];
    __syncthreads();

    for (int n = wave; n < 129; n += 4) {            // fc5
        float acc = 0.f;
        for (int k = lane; k < 512; k += 64) acc += w5[n * 512 + k] * xs[k];
#pragma unroll
        for (int o = 32; o; o >>= 1) acc += __shfl_xor(acc, o);
        if (lane == 0) ys[n] = acc + b5[n];
    }
    __syncthreads();

    for (int n = wave; n < 129; n += 4) {            // fc6
        float acc = 0.f;
        for (int k = lane; k < 258; k += 64) acc += w6[n * 258 + k] * ys[k];
#pragma unroll
        for (int o = 32; o; o >>= 1) acc += __shfl_xor(acc, o);
        if (lane == 0) scs[n] = acc + b6[n];
    }
    __syncthreads();

    if (tid < 129) {                                 // exact rank (ties: lower idx first)
        const float x = scs[tid];
        int cnt = 0;
        for (int j = 0; j < 129; ++j) {
            const float sj = scs[j];
            cnt += (sj > x) || (sj == x && j < tid);
        }
        win[tid] = (cnt < 64) ? 1 : 0;
    }
    __syncthreads();

    if (tid < 64) {                                  // max over winners
        float m = -3.402823466e38f;
        for (int j = tid; j < 129; j += 64) if (win[j]) m = fmaxf(m, scs[j]);
#pragma unroll
        for (int o = 32; o; o >>= 1) m = fmaxf(m, __shfl_xor(m, o));
        if (tid == 0) red[0] = m;
    }
    __syncthreads();
    if (tid < 129) scs[tid] = win[tid] ? expf(scs[tid] - red[0]) : 0.f;
    __syncthreads();
    if (tid < 64) {
        float s = 0.f;
        for (int j = tid; j < 129; j += 64) s += scs[j];
#pragma unroll
        for (int o = 32; o; o >>= 1) s += __shfl_xor(s, o);
        if (tid == 0) red[1] = s;
    }
    __syncthreads();
    if (tid < 129) out[b * 129 + tid] = scs[tid] / red[1];
}

// ---------------------------------------------------------------------------
extern "C" void kernel_launch(void* const* d_in, const int* in_sizes, int n_in,
                              void* d_out, int out_size, void* d_ws, size_t ws_size,
                              hipStream_t stream) {
    (void)in_sizes; (void)n_in; (void)out_size; (void)ws_size;
    const float* hist  = (const float*)d_in[0];
    const float* la    = (const float*)d_in[1];
    const float* emb_w = (const float*)d_in[2];
    const float* emb_b = (const float*)d_in[3];
    const float* inp_w = (const float*)d_in[4];
    const float* inp_b = (const float*)d_in[5];
    const float* out_w = (const float*)d_in[6];
    const float* out_b = (const float*)d_in[7];
    const float* ln_g  = (const float*)d_in[8];
    const float* ln_b  = (const float*)d_in[9];
    const float* w1    = (const float*)d_in[10];
    const float* b1    = (const float*)d_in[11];
    const float* w2    = (const float*)d_in[12];
    const float* b2    = (const float*)d_in[13];
    const float* l1g   = (const float*)d_in[14];
    const float* l1b   = (const float*)d_in[15];
    const float* w3    = (const float*)d_in[16];
    const float* b3    = (const float*)d_in[17];
    const float* w4    = (const float*)d_in[18];
    const float* b4    = (const float*)d_in[19];
    const float* w5    = (const float*)d_in[20];
    const float* b5    = (const float*)d_in[21];
    const float* w6    = (const float*)d_in[22];
    const float* b6    = (const float*)d_in[23];

    char* ws = (char*)d_ws;
    float* bufH   = (float*)(ws + WS_OFF_H);
    float* bufQKV = (float*)(ws + WS_OFF_QKV);
    float* c1     = (float*)(ws + WS_OFF_C1);
    float* c2     = (float*)(ws + WS_OFF_C2);
    float* c3     = (float*)(ws + WS_OFF_C3);
    float* c4     = (float*)(ws + WS_OFF_C4);
    float* x1     = (float*)(ws + WS_OFF_X1);
    float* x2     = (float*)(ws + WS_OFF_X2);
    float* x3     = (float*)(ws + WS_OFF_X3);
    float* x4     = (float*)(ws + WS_OFF_X4);

    hipMemsetAsync(ws + WS_OFF_C1, 0, (size_t)WS_ZERO_LEN, stream);

    // 1) h = hist @ emb_w^T + emb_b           [65536,640]
    {
        GemmP p{hist, emb_w, bufH, emb_b, nullptr, 640, 640, 640, 0, 0, 640, 640, 0, 0};
        gemm128<false><<<dim3(512, 5, 1), 256, 0, stream>>>(p);
    }
    // 2) qkv = h @ inp_w^T + inp_b            [65536,1920]
    {
        GemmP p{bufH, inp_w, bufQKV, inp_b, nullptr, 640, 640, 1920, 0, 0, 640, 640, 0, 0};
        gemm128<false><<<dim3(512, 15, 1), 256, 0, stream>>>(p);
    }
    // 3) attention (ctx written over q slice)
    attn_kernel<<<dim3(BB * NH), 256, 0, stream>>>(bufQKV);
    // 4) attn_out + h  -> qkv k-slice         (A = ctx = q slice)
    {
        GemmP p{bufQKV, out_w, bufQKV + 640, out_b, bufH, 1920, 640, 1920, 640, 0, 640, 640, 0, 0};
        gemm128<false><<<dim3(512, 5, 1), 256, 0, stream>>>(p);
    }
    // 5) X = LN(attn_out + h) -> bufH (h dead after step 4)
    ln640_kernel<<<dim3(16384), 256, 0, stream>>>(bufQKV + 640, bufH, ln_g, ln_b);
    // 6) fc1 main: [512,81920] @ w1[:, :81920]^T  (split-K 16, atomic)
    {
        GemmP p{bufH, w1, c1, nullptr, nullptr, 81920, 82049, 2048, 0, 0, 81920, 5120, 0, 0};
        gemm128<true><<<dim3(4, 16, 16), 256, 0, stream>>>(p);
    }
    // 6b) fc1 tail: last_action @ w1[:, 81920:]^T
    {
        GemmP p{la, w1, c1, nullptr, nullptr, 129, 82049, 2048, 0, 81920, 82049, 129, 81920, 0};
        gemm128<true><<<dim3(4, 16, 1), 256, 0, stream>>>(p);
    }
    bias_relu_kernel<<<dim3(4096), 256, 0, stream>>>(c1, b1, x1, 2047);
    // 7) fc2 (split-K 4, atomic) ; then X2 = LN(relu(c2+b2)+x1)
    {
        GemmP p{x1, w2, c2, nullptr, nullptr, 2048, 2048, 2048, 0, 0, 2048, 512, 0, 0};
        gemm128<true><<<dim3(4, 16, 4), 256, 0, stream>>>(p);
    }
    ln2048_kernel<<<dim3(128), 256, 0, stream>>>(c2, b2, x1, l1g, l1b, x2);
    // 8) fc3 (split-K 8)
    {
        GemmP p{x2, w3, c3, nullptr, nullptr, 2048, 2048, 1024, 0, 0, 2048, 256, 0, 0};
        gemm128<true><<<dim3(4, 8, 8), 256, 0, stream>>>(p);
    }
    bias_relu_kernel<<<dim3(2048), 256, 0, stream>>>(c3, b3, x3, 1023);
    // 9) fc4 (split-K 8)
    {
        GemmP p{x3, w4, c4, nullptr, nullptr, 1024, 1024, 512, 0, 0, 1024, 128, 0, 0};
        gemm128<true><<<dim3(4, 4, 8), 256, 0, stream>>>(p);
    }
    bias_relu_kernel<<<dim3(1024), 256, 0, stream>>>(c4, b4, x4, 511);
    // 10) head: fc5 -> concat -> fc6 -> top-64 -> softmax
    head_kernel<<<dim3(512), 256, 0, stream>>>(x4, la, w5, b5, w6, b6, (float*)d_out);
}